// Round 1
// baseline (6235.367 us; speedup 1.0000x reference)
//
#include <hip/hip_runtime.h>
#include <cstdint>
#include <cstddef>

// Problem constants
#define B_DIM 4
#define H_DIM 200
#define W_DIM 176
#define CCH 256
#define NPP 16384        // points per batch entry (N)
#define NPTS 65536       // total points (P)
#define HW 35200         // H*W
#define S_TOT 140800     // B*H*W
#define EPS 1e-3f
#define INV_S (1.0f/140800.0f)

// ---------------------------------------------------------------- scatter ----
__global__ __launch_bounds__(256) void k_scatter_cnt(
    const int* __restrict__ cb, const int* __restrict__ cy,
    const int* __restrict__ cx, float* __restrict__ cnt)
{
    int p = blockIdx.x * 256 + threadIdx.x;
    int vid = cb[p] * HW + cy[p] * W_DIM + cx[p];
    atomicAdd(&cnt[vid], 1.0f);
}

__global__ __launch_bounds__(256) void k_scatter_feat(
    const float* __restrict__ feats, const int* __restrict__ cb,
    const int* __restrict__ cy, const int* __restrict__ cx,
    float* __restrict__ sums)
{
    int p = blockIdx.x * 256 + threadIdx.x;   // point id
    int c = blockIdx.y * 4;                   // channel group
    int b = p >> 14;                          // p / NPP
    int n = p & (NPP - 1);
    int vid = cb[p] * HW + cy[p] * W_DIM + cx[p];
    const float* f = feats + ((size_t)b * CCH + c) * NPP + n;
    float* dst = sums + (size_t)vid * CCH + c;
    atomicAdd(dst + 0, f[0]);
    atomicAdd(dst + 1, f[(size_t)NPP]);
    atomicAdd(dst + 2, f[(size_t)2 * NPP]);
    atomicAdd(dst + 3, f[(size_t)3 * NPP]);
}

__global__ __launch_bounds__(256) void k_pool(
    float* __restrict__ sums, const float* __restrict__ cnt)
{
    size_t q = (size_t)blockIdx.x * 256 + threadIdx.x;  // float4 index
    int row = (int)(q >> 6);                            // 64 float4 per row
    float inv = 1.0f / fmaxf(cnt[row], 1.0f);
    float4* p = (float4*)sums;
    float4 v = p[q];
    v.x *= inv; v.y *= inv; v.z *= inv; v.w *= inv;
    p[q] = v;
}

// ---------------------------------------------------------------- GEMM -------
// Y[M,N] = trans(A)[M,K] @ W[K,N];  trans = bn+relu per K-column if ts != null
// BM=BN=128, BK=16, 256 threads, 8x8 micro-tile. M assumed multiple of 128.
__global__ __launch_bounds__(256) void k_gemm(
    const float* __restrict__ A, const float* __restrict__ Wt,
    float* __restrict__ Y, int N, int K,
    const float* __restrict__ ts, const float* __restrict__ tb)
{
    __shared__ float As[16][132];
    __shared__ float Ws[16][132];
    const int tid = threadIdx.x;
    const int bm = blockIdx.x * 128;
    const int bn = blockIdx.y * 128;
    const int r0 = (tid >> 4) * 8;
    const int c0 = (tid & 15) * 8;
    const int lrow = tid >> 1;          // 0..127  (A load row)
    const int lkk  = (tid & 1) * 8;     // 0 or 8  (A load k offset)
    const int wk   = tid >> 4;          // 0..15   (W load k)
    const int wn   = (tid & 15) * 8;    // W load col
    float acc[8][8] = {};

    for (int k0 = 0; k0 < K; k0 += 16) {
        // --- stage A tile (128 x 16), optional bn+relu transform
        const float* ap = A + (size_t)(bm + lrow) * K + k0 + lkk;
        float4 a0 = *(const float4*)ap;
        float4 a1 = *(const float4*)(ap + 4);
        if (ts) {
            int kk = k0 + lkk;
            a0.x = fmaxf(0.f, a0.x * ts[kk + 0] + tb[kk + 0]);
            a0.y = fmaxf(0.f, a0.y * ts[kk + 1] + tb[kk + 1]);
            a0.z = fmaxf(0.f, a0.z * ts[kk + 2] + tb[kk + 2]);
            a0.w = fmaxf(0.f, a0.w * ts[kk + 3] + tb[kk + 3]);
            a1.x = fmaxf(0.f, a1.x * ts[kk + 4] + tb[kk + 4]);
            a1.y = fmaxf(0.f, a1.y * ts[kk + 5] + tb[kk + 5]);
            a1.z = fmaxf(0.f, a1.z * ts[kk + 6] + tb[kk + 6]);
            a1.w = fmaxf(0.f, a1.w * ts[kk + 7] + tb[kk + 7]);
        }
        As[lkk + 0][lrow] = a0.x; As[lkk + 1][lrow] = a0.y;
        As[lkk + 2][lrow] = a0.z; As[lkk + 3][lrow] = a0.w;
        As[lkk + 4][lrow] = a1.x; As[lkk + 5][lrow] = a1.y;
        As[lkk + 6][lrow] = a1.z; As[lkk + 7][lrow] = a1.w;
        // --- stage W tile (16 x 128)
        const float* wp = Wt + (size_t)(k0 + wk) * N + bn + wn;
        *(float4*)&Ws[wk][wn]     = *(const float4*)wp;
        *(float4*)&Ws[wk][wn + 4] = *(const float4*)(wp + 4);
        __syncthreads();
#pragma unroll
        for (int k = 0; k < 16; ++k) {
            float a[8], b[8];
            *(float4*)&a[0] = *(float4*)&As[k][r0];
            *(float4*)&a[4] = *(float4*)&As[k][r0 + 4];
            *(float4*)&b[0] = *(float4*)&Ws[k][c0];
            *(float4*)&b[4] = *(float4*)&Ws[k][c0 + 4];
#pragma unroll
            for (int i = 0; i < 8; ++i)
#pragma unroll
                for (int j = 0; j < 8; ++j)
                    acc[i][j] = fmaf(a[i], b[j], acc[i][j]);
        }
        __syncthreads();
    }
#pragma unroll
    for (int i = 0; i < 8; ++i) {
        float* yr = Y + (size_t)(bm + r0 + i) * N + bn + c0;
        *(float4*)&yr[0] = make_float4(acc[i][0], acc[i][1], acc[i][2], acc[i][3]);
        *(float4*)&yr[4] = make_float4(acc[i][4], acc[i][5], acc[i][6], acc[i][7]);
    }
}

// ---------------------------------------------------------------- conv3x3 ----
// Y[S,256] = conv3x3(trans(X) as [B,H,W,256]) @ Wc[3,3,256,256] (+bias)
// trans = bn+relu per channel if ts != null. Zero padding applied AFTER trans.
__global__ __launch_bounds__(256) void k_conv(
    const float* __restrict__ X, const float* __restrict__ Wc,
    float* __restrict__ Y,
    const float* __restrict__ ts, const float* __restrict__ tb,
    const float* __restrict__ bias)
{
    __shared__ float As[16][132];
    __shared__ float Ws[16][132];
    const int tid = threadIdx.x;
    const int bm = blockIdx.x * 128;
    const int bn = blockIdx.y * 128;
    const int r0 = (tid >> 4) * 8;
    const int c0 = (tid & 15) * 8;
    const int lrow = tid >> 1;
    const int lkk  = (tid & 1) * 8;
    const int wk   = tid >> 4;
    const int wn   = (tid & 15) * 8;
    float acc[8][8] = {};

    const int s = bm + lrow;                 // my load row's spatial index
    const int wcol = s % W_DIM;
    const int hrow = (s / W_DIM) % H_DIM;

    for (int pos = 0; pos < 9; ++pos) {
        const int dy = pos / 3 - 1, dx = pos % 3 - 1;
        const bool ok = (hrow + dy >= 0) && (hrow + dy < H_DIM) &&
                        (wcol + dx >= 0) && (wcol + dx < W_DIM);
        const float* xp = X + ((size_t)s + (size_t)(dy * W_DIM + dx)) * CCH;
        const float* wbase = Wc + (size_t)pos * CCH * CCH;
        for (int kc = 0; kc < CCH; kc += 16) {
            float4 a0 = make_float4(0.f, 0.f, 0.f, 0.f);
            float4 a1 = a0;
            if (ok) {
                a0 = *(const float4*)(xp + kc + lkk);
                a1 = *(const float4*)(xp + kc + lkk + 4);
                if (ts) {
                    int kk = kc + lkk;
                    a0.x = fmaxf(0.f, a0.x * ts[kk + 0] + tb[kk + 0]);
                    a0.y = fmaxf(0.f, a0.y * ts[kk + 1] + tb[kk + 1]);
                    a0.z = fmaxf(0.f, a0.z * ts[kk + 2] + tb[kk + 2]);
                    a0.w = fmaxf(0.f, a0.w * ts[kk + 3] + tb[kk + 3]);
                    a1.x = fmaxf(0.f, a1.x * ts[kk + 4] + tb[kk + 4]);
                    a1.y = fmaxf(0.f, a1.y * ts[kk + 5] + tb[kk + 5]);
                    a1.z = fmaxf(0.f, a1.z * ts[kk + 6] + tb[kk + 6]);
                    a1.w = fmaxf(0.f, a1.w * ts[kk + 7] + tb[kk + 7]);
                }
            }
            As[lkk + 0][lrow] = a0.x; As[lkk + 1][lrow] = a0.y;
            As[lkk + 2][lrow] = a0.z; As[lkk + 3][lrow] = a0.w;
            As[lkk + 4][lrow] = a1.x; As[lkk + 5][lrow] = a1.y;
            As[lkk + 6][lrow] = a1.z; As[lkk + 7][lrow] = a1.w;
            const float* wp = wbase + (size_t)(kc + wk) * CCH + bn + wn;
            *(float4*)&Ws[wk][wn]     = *(const float4*)wp;
            *(float4*)&Ws[wk][wn + 4] = *(const float4*)(wp + 4);
            __syncthreads();
#pragma unroll
            for (int k = 0; k < 16; ++k) {
                float a[8], b[8];
                *(float4*)&a[0] = *(float4*)&As[k][r0];
                *(float4*)&a[4] = *(float4*)&As[k][r0 + 4];
                *(float4*)&b[0] = *(float4*)&Ws[k][c0];
                *(float4*)&b[4] = *(float4*)&Ws[k][c0 + 4];
#pragma unroll
                for (int i = 0; i < 8; ++i)
#pragma unroll
                    for (int j = 0; j < 8; ++j)
                        acc[i][j] = fmaf(a[i], b[j], acc[i][j]);
            }
            __syncthreads();
        }
    }
#pragma unroll
    for (int i = 0; i < 8; ++i) {
        float* yr = Y + (size_t)(bm + r0 + i) * CCH + bn + c0;
        float bj[8];
#pragma unroll
        for (int j = 0; j < 8; ++j)
            bj[j] = acc[i][j] + (bias ? bias[bn + c0 + j] : 0.f);
        *(float4*)&yr[0] = make_float4(bj[0], bj[1], bj[2], bj[3]);
        *(float4*)&yr[4] = make_float4(bj[4], bj[5], bj[6], bj[7]);
    }
}

// ---------------------------------------------------------------- BN stats ---
// blockDim.x == ncols; 256 rows per block; acc layout: [ncols sums][ncols sq]
__global__ void k_colstats(const float* __restrict__ Y, float* __restrict__ acc)
{
    const int ncols = blockDim.x;
    const int col = threadIdx.x;
    const int r0 = blockIdx.x * 256;
    float s = 0.f, q = 0.f;
    const float* p = Y + (size_t)r0 * ncols + col;
    for (int r = 0; r < 256; ++r, p += ncols) {
        float v = *p;
        s += v; q += v * v;
    }
    atomicAdd(&acc[col], s);
    atomicAdd(&acc[ncols + col], q);
}

// par layout: [ncols scale][ncols shift]
__global__ void k_bnparams(const float* __restrict__ acc,
                           const float* __restrict__ g,
                           const float* __restrict__ b,
                           float* __restrict__ par, int ncols)
{
    int c = threadIdx.x;
    if (c >= ncols) return;
    float m = acc[c] * INV_S;
    float v = acc[ncols + c] * INV_S - m * m;
    float sc = g[c] * rsqrtf(v + EPS);
    par[c] = sc;
    par[ncols + c] = b[c] - m * sc;
}

// ---------------------------------------------------------------- head -------
// per row s: shdc = dot(bnrelu(B2[s,:]), sh_w3[:,0]) + sh_bias3[0]
//            gaus = sigmoid(dot(bnrelu(B3[s,:]), g_w3) + g_bias3[0])
//            sp[s,:] = pooled[s,:] * gaus * shdc
__global__ __launch_bounds__(256) void k_headfin(
    const float* __restrict__ B2, const float* __restrict__ B3,
    const float* __restrict__ par1, const float* __restrict__ par3,
    const float* __restrict__ shw3, const float* __restrict__ shb3,
    const float* __restrict__ gw3, const float* __restrict__ gb3,
    const float* __restrict__ pooled, float* __restrict__ sp)
{
    const int wave = threadIdx.x >> 6;
    const int lane = threadIdx.x & 63;
    const int s = blockIdx.x * 4 + wave;
    const float* b2 = B2 + (size_t)s * 256;
    const float* b3 = B3 + (size_t)s * 128;
    float d1 = 0.f, d2 = 0.f;
#pragma unroll
    for (int i = 0; i < 4; ++i) {
        int c = lane * 4 + i;
        float v = fmaxf(0.f, b2[c] * par1[c] + par1[256 + c]);
        d1 += v * shw3[c * 9];          // column 0 of [256,9]
    }
#pragma unroll
    for (int i = 0; i < 2; ++i) {
        int c = lane * 2 + i;
        float v = fmaxf(0.f, b3[c] * par3[c] + par3[128 + c]);
        d2 += v * gw3[c];
    }
#pragma unroll
    for (int off = 32; off > 0; off >>= 1) {
        d1 += __shfl_down(d1, off, 64);
        d2 += __shfl_down(d2, off, 64);
    }
    d1 = __shfl(d1, 0, 64);
    d2 = __shfl(d2, 0, 64);
    float shdc = d1 + shb3[0];
    float gaus = 1.f / (1.f + expf(-(d2 + gb3[0])));
    float factor = shdc * gaus;
    const float4* pr = (const float4*)(pooled + (size_t)s * 256);
    float4* spr = (float4*)(sp + (size_t)s * 256);
    float4 v = pr[lane];
    v.x *= factor; v.y *= factor; v.z *= factor; v.w *= factor;
    spr[lane] = v;
}

// ---------------------------------------------------------------- final ------
__global__ __launch_bounds__(256) void k_bnrelu_inplace(
    float* __restrict__ Y, const float* __restrict__ par)
{
    size_t q = (size_t)blockIdx.x * 256 + threadIdx.x;  // float4 index
    int c = (int)(q & 63) * 4;                          // channel of .x
    float4* p = (float4*)Y;
    float4 v = p[q];
    v.x = fmaxf(0.f, v.x * par[c + 0] + par[256 + c + 0]);
    v.y = fmaxf(0.f, v.y * par[c + 1] + par[256 + c + 1]);
    v.z = fmaxf(0.f, v.z * par[c + 2] + par[256 + c + 2]);
    v.w = fmaxf(0.f, v.w * par[c + 3] + par[256 + c + 3]);
    p[q] = v;
}

// ---------------------------------------------------------------- launch -----
extern "C" void kernel_launch(void* const* d_in, const int* in_sizes, int n_in,
                              void* d_out, int out_size, void* d_ws, size_t ws_size,
                              hipStream_t stream)
{
    (void)in_sizes; (void)n_in; (void)out_size; (void)ws_size;
    const float* feats   = (const float*)d_in[0];
    const int*   cb      = (const int*)d_in[1];
    const int*   cy      = (const int*)d_in[2];
    const int*   cx      = (const int*)d_in[3];
    const float* sh_w1   = (const float*)d_in[4];
    const float* sh_g1   = (const float*)d_in[5];
    const float* sh_b1   = (const float*)d_in[6];
    const float* sh_w2   = (const float*)d_in[7];
    const float* sh_g2   = (const float*)d_in[8];
    const float* sh_b2   = (const float*)d_in[9];
    const float* sh_w3   = (const float*)d_in[10];
    const float* sh_bias3= (const float*)d_in[11];
    const float* g_w1    = (const float*)d_in[12];
    const float* g_g1    = (const float*)d_in[13];
    const float* g_b1    = (const float*)d_in[14];
    const float* g_w2    = (const float*)d_in[15];
    const float* g_g2    = (const float*)d_in[16];
    const float* g_b2    = (const float*)d_in[17];
    const float* g_w3    = (const float*)d_in[18];
    const float* g_bias3 = (const float*)d_in[19];
    const float* cw1     = (const float*)d_in[20];
    const float* c1_g    = (const float*)d_in[21];
    const float* c1_b    = (const float*)d_in[22];
    const float* cw2     = (const float*)d_in[23];
    const float* c2_bias = (const float*)d_in[24];
    const float* c2_g    = (const float*)d_in[25];
    const float* c2_b    = (const float*)d_in[26];

    float* out = (float*)d_out;               // also used as scratch B1
    float* ws  = (float*)d_ws;
    const size_t SB = (size_t)S_TOT * CCH;    // 36,044,800 floats
    float* P0  = ws;                          // pooled (sums)
    float* B2  = ws + SB;
    float* B3  = ws + 2 * SB;                 // only S*128 used
    float* CNT = ws + 2 * SB + (size_t)S_TOT * 128;
    float* ACC = CNT + S_TOT;                 // 6 * 512 floats
    float* PAR = ACC + 6 * 512;               // 6 * 512 floats
    float* B1  = out;

    // zero accumulators (every launch: graph replays must be deterministic)
    hipMemsetAsync(P0, 0, SB * sizeof(float), stream);
    hipMemsetAsync(CNT, 0, (size_t)(S_TOT + 6 * 512) * sizeof(float), stream);

    // 1) scatter-mean pooling
    k_scatter_cnt<<<NPTS / 256, 256, 0, stream>>>(cb, cy, cx, CNT);
    k_scatter_feat<<<dim3(NPTS / 256, 64), 256, 0, stream>>>(feats, cb, cy, cx, P0);
    k_pool<<<35200, 256, 0, stream>>>(P0, CNT);

    // 2) SH head layer 1: B1 = P0 @ sh_w1 ; stats ; params
    k_gemm<<<dim3(1100, 2), 256, 0, stream>>>(P0, sh_w1, B1, 256, 256, nullptr, nullptr);
    k_colstats<<<550, 256, 0, stream>>>(B1, ACC + 0 * 512);
    k_bnparams<<<1, 256, 0, stream>>>(ACC + 0 * 512, sh_g1, sh_b1, PAR + 0 * 512, 256);
    // 3) SH head layer 2: B2 = bnrelu(B1) @ sh_w2
    k_gemm<<<dim3(1100, 2), 256, 0, stream>>>(B1, sh_w2, B2, 256, 256,
                                              PAR + 0 * 512, PAR + 0 * 512 + 256);
    k_colstats<<<550, 256, 0, stream>>>(B2, ACC + 1 * 512);
    k_bnparams<<<1, 256, 0, stream>>>(ACC + 1 * 512, sh_g2, sh_b2, PAR + 1 * 512, 256);
    // 4) G head layer 1: B1 = P0 @ g_w1
    k_gemm<<<dim3(1100, 2), 256, 0, stream>>>(P0, g_w1, B1, 256, 256, nullptr, nullptr);
    k_colstats<<<550, 256, 0, stream>>>(B1, ACC + 2 * 512);
    k_bnparams<<<1, 256, 0, stream>>>(ACC + 2 * 512, g_g1, g_b1, PAR + 2 * 512, 256);
    // 5) G head layer 2: B3 = bnrelu(B1) @ g_w2   (N = 128)
    k_gemm<<<dim3(1100, 1), 256, 0, stream>>>(B1, g_w2, B3, 128, 256,
                                              PAR + 2 * 512, PAR + 2 * 512 + 256);
    k_colstats<<<550, 128, 0, stream>>>(B3, ACC + 3 * 512);
    k_bnparams<<<1, 128, 0, stream>>>(ACC + 3 * 512, g_g2, g_b2, PAR + 3 * 512, 128);
    // 6) head finalize: sp -> B1 (=out, free now)
    k_headfin<<<35200, 256, 0, stream>>>(B2, B3, PAR + 1 * 512, PAR + 3 * 512,
                                         sh_w3, sh_bias3, g_w3, g_bias3, P0, B1);
    // 7) conv1: B2 = conv3x3(B1)
    k_conv<<<dim3(1100, 2), 256, 0, stream>>>(B1, cw1, B2, nullptr, nullptr, nullptr);
    k_colstats<<<550, 256, 0, stream>>>(B2, ACC + 4 * 512);
    k_bnparams<<<1, 256, 0, stream>>>(ACC + 4 * 512, c1_g, c1_b, PAR + 4 * 512, 256);
    // 8) conv2: out = conv3x3(bnrelu(B2)) + bias
    k_conv<<<dim3(1100, 2), 256, 0, stream>>>(B2, cw2, out,
                                              PAR + 4 * 512, PAR + 4 * 512 + 256, c2_bias);
    k_colstats<<<550, 256, 0, stream>>>(out, ACC + 5 * 512);
    k_bnparams<<<1, 256, 0, stream>>>(ACC + 5 * 512, c2_g, c2_b, PAR + 5 * 512, 256);
    // 9) final BN+ReLU in place on out
    k_bnrelu_inplace<<<35200, 256, 0, stream>>>(out, PAR + 5 * 512);
}

// Round 2
// 2490.167 us; speedup vs baseline: 2.5040x; 2.5040x over previous
//
#include <hip/hip_runtime.h>
#include <hip/hip_bf16.h>
#include <cstdint>
#include <cstddef>

// Problem constants
#define B_DIM 4
#define H_DIM 200
#define W_DIM 176
#define CCH 256
#define NPP 16384        // points per batch entry (N)
#define NPTS 65536       // total points (P)
#define HW 35200         // H*W
#define S_TOT 140800     // B*H*W
#define EPS 1e-3f
#define INV_S (1.0f/140800.0f)

typedef unsigned short ushort_t;
typedef __attribute__((ext_vector_type(8))) short bf16x8;
typedef __attribute__((ext_vector_type(4))) float f32x4;

__device__ __forceinline__ ushort_t f2bf(float f) {
    __hip_bfloat16 h = __float2bfloat16(f);   // RNE
    return *(ushort_t*)&h;
}

__device__ __forceinline__ void async16(const void* g, void* l) {
    __builtin_amdgcn_global_load_lds(
        (const __attribute__((address_space(1))) unsigned int*)g,
        (__attribute__((address_space(3))) unsigned int*)l,
        16, 0, 0);
}

// ---------------------------------------------------------------- scatter ----
__global__ __launch_bounds__(256) void k_scatter_cnt(
    const int* __restrict__ cb, const int* __restrict__ cy,
    const int* __restrict__ cx, float* __restrict__ cnt)
{
    int p = blockIdx.x * 256 + threadIdx.x;
    int vid = cb[p] * HW + cy[p] * W_DIM + cx[p];
    atomicAdd(&cnt[vid], 1.0f);
}

__global__ __launch_bounds__(256) void k_scatter_feat(
    const float* __restrict__ feats, const int* __restrict__ cb,
    const int* __restrict__ cy, const int* __restrict__ cx,
    float* __restrict__ sums)
{
    int p = blockIdx.x * 256 + threadIdx.x;   // point id
    int c = blockIdx.y * 4;                   // channel group
    int b = p >> 14;                          // p / NPP
    int n = p & (NPP - 1);
    int vid = cb[p] * HW + cy[p] * W_DIM + cx[p];
    const float* f = feats + ((size_t)b * CCH + c) * NPP + n;
    float* dst = sums + (size_t)vid * CCH + c;
    atomicAdd(dst + 0, f[0]);
    atomicAdd(dst + 1, f[(size_t)NPP]);
    atomicAdd(dst + 2, f[(size_t)2 * NPP]);
    atomicAdd(dst + 3, f[(size_t)3 * NPP]);
}

__global__ __launch_bounds__(256) void k_pool(
    float* __restrict__ sums, const float* __restrict__ cnt)
{
    size_t q = (size_t)blockIdx.x * 256 + threadIdx.x;  // float4 index
    int row = (int)(q >> 6);                            // 64 float4 per row
    float inv = 1.0f / fmaxf(cnt[row], 1.0f);
    float4* p = (float4*)sums;
    float4 v = p[q];
    v.x *= inv; v.y *= inv; v.z *= inv; v.w *= inv;
    p[q] = v;
}

// ---------------------------------------------------------------- GEMM (f32) -
// Y[M,N] = trans(A)[M,K] @ W[K,N];  trans = bn+relu per K-column if ts != null
__global__ __launch_bounds__(256) void k_gemm(
    const float* __restrict__ A, const float* __restrict__ Wt,
    float* __restrict__ Y, int N, int K,
    const float* __restrict__ ts, const float* __restrict__ tb)
{
    __shared__ float As[16][132];
    __shared__ float Ws[16][132];
    const int tid = threadIdx.x;
    const int bm = blockIdx.x * 128;
    const int bn = blockIdx.y * 128;
    const int r0 = (tid >> 4) * 8;
    const int c0 = (tid & 15) * 8;
    const int lrow = tid >> 1;
    const int lkk  = (tid & 1) * 8;
    const int wk   = tid >> 4;
    const int wn   = (tid & 15) * 8;
    float acc[8][8] = {};

    for (int k0 = 0; k0 < K; k0 += 16) {
        const float* ap = A + (size_t)(bm + lrow) * K + k0 + lkk;
        float4 a0 = *(const float4*)ap;
        float4 a1 = *(const float4*)(ap + 4);
        if (ts) {
            int kk = k0 + lkk;
            a0.x = fmaxf(0.f, a0.x * ts[kk + 0] + tb[kk + 0]);
            a0.y = fmaxf(0.f, a0.y * ts[kk + 1] + tb[kk + 1]);
            a0.z = fmaxf(0.f, a0.z * ts[kk + 2] + tb[kk + 2]);
            a0.w = fmaxf(0.f, a0.w * ts[kk + 3] + tb[kk + 3]);
            a1.x = fmaxf(0.f, a1.x * ts[kk + 4] + tb[kk + 4]);
            a1.y = fmaxf(0.f, a1.y * ts[kk + 5] + tb[kk + 5]);
            a1.z = fmaxf(0.f, a1.z * ts[kk + 6] + tb[kk + 6]);
            a1.w = fmaxf(0.f, a1.w * ts[kk + 7] + tb[kk + 7]);
        }
        As[lkk + 0][lrow] = a0.x; As[lkk + 1][lrow] = a0.y;
        As[lkk + 2][lrow] = a0.z; As[lkk + 3][lrow] = a0.w;
        As[lkk + 4][lrow] = a1.x; As[lkk + 5][lrow] = a1.y;
        As[lkk + 6][lrow] = a1.z; As[lkk + 7][lrow] = a1.w;
        const float* wp = Wt + (size_t)(k0 + wk) * N + bn + wn;
        *(float4*)&Ws[wk][wn]     = *(const float4*)wp;
        *(float4*)&Ws[wk][wn + 4] = *(const float4*)(wp + 4);
        __syncthreads();
#pragma unroll
        for (int k = 0; k < 16; ++k) {
            float a[8], b[8];
            *(float4*)&a[0] = *(float4*)&As[k][r0];
            *(float4*)&a[4] = *(float4*)&As[k][r0 + 4];
            *(float4*)&b[0] = *(float4*)&Ws[k][c0];
            *(float4*)&b[4] = *(float4*)&Ws[k][c0 + 4];
#pragma unroll
            for (int i = 0; i < 8; ++i)
#pragma unroll
                for (int j = 0; j < 8; ++j)
                    acc[i][j] = fmaf(a[i], b[j], acc[i][j]);
        }
        __syncthreads();
    }
#pragma unroll
    for (int i = 0; i < 8; ++i) {
        float* yr = Y + (size_t)(bm + r0 + i) * N + bn + c0;
        *(float4*)&yr[0] = make_float4(acc[i][0], acc[i][1], acc[i][2], acc[i][3]);
        *(float4*)&yr[4] = make_float4(acc[i][4], acc[i][5], acc[i][6], acc[i][7]);
    }
}

// ---------------------------------------------------------------- conv MFMA --
// Y[S,256] = conv3x3(X as [B,H,W,256] bf16) @ Wt[9][co][ci] bf16 (+bias)
// BM=BN=128, BK=64, 4 waves each computing 64x64 via 4x4 frags of 16x16x32.
// LDS tiles [128 rows][64 k] bf16, XOR-swizzled 16B units: q_phys = q ^ (row&7).
// Staged via global_load_lds (linear dest); source pre-swizzled per lane;
// OOB halo rows redirected to a zero page.
__global__ __launch_bounds__(256) void k_convmma(
    const ushort_t* __restrict__ X,      // [S][256] bf16
    const ushort_t* __restrict__ Wt,     // [9][256 co][256 ci] bf16
    float* __restrict__ Y,               // [S][256] f32
    const float* __restrict__ bias,      // null or [256]
    const ushort_t* __restrict__ zp)     // >=4KB zeros
{
    __shared__ ushort_t Asm[128 * 64];
    __shared__ ushort_t Bsm[128 * 64];
    const int tid  = threadIdx.x;
    const int w    = tid >> 6;
    const int lane = tid & 63;
    const int bm   = blockIdx.x * 128;
    const int bn   = blockIdx.y * 128;
    const int wr   = (w >> 1) * 64;      // wave row offset in tile
    const int wc   = (w & 1) * 64;       // wave col offset in tile

    // staging geometry: wave w covers tile rows [32w, 32w+32), 4 issues x 8 rows
    int yj[4], xj[4];
    const ushort_t* abase[4];            // A source base (pos/kc-independent)
    int boff[4];                         // B source offset (pos/kc-independent)
#pragma unroll
    for (int j = 0; j < 4; ++j) {
        int row  = 32 * w + 8 * j + (lane >> 3);
        int qlog = (lane & 7) ^ (row & 7);
        int s    = bm + row;
        yj[j] = (s / W_DIM) % H_DIM;
        xj[j] = s % W_DIM;
        abase[j] = X + (size_t)s * CCH + qlog * 8;
        boff[j]  = (bn + row) * CCH + qlog * 8;
    }

    f32x4 acc[4][4] = {};

    for (int pos = 0; pos < 9; ++pos) {
        const int dy = pos / 3 - 1, dx = pos % 3 - 1;
        const ushort_t* bw = Wt + pos * (CCH * CCH);
        const ushort_t* ap[4];
#pragma unroll
        for (int j = 0; j < 4; ++j) {
            bool ok = ((unsigned)(yj[j] + dy) < (unsigned)H_DIM) &&
                      ((unsigned)(xj[j] + dx) < (unsigned)W_DIM);
            ap[j] = ok ? abase[j] + (dy * W_DIM + dx) * CCH : zp + lane * 8;
        }
        for (int kc = 0; kc < CCH; kc += 64) {
#pragma unroll
            for (int j = 0; j < 4; ++j)
                async16(ap[j] + kc, Asm + w * 2048 + j * 512);
#pragma unroll
            for (int j = 0; j < 4; ++j)
                async16(bw + boff[j] + kc, Bsm + w * 2048 + j * 512);
            __syncthreads();
#pragma unroll
            for (int ks = 0; ks < 2; ++ks) {
                bf16x8 af[4], bfr[4];
                const int qs = (ks * 4 + (lane >> 4)) ^ (lane & 7);
#pragma unroll
                for (int i = 0; i < 4; ++i) {
                    int r  = wr + i * 16 + (lane & 15);
                    af[i]  = *(const bf16x8*)&Asm[r * 64 + qs * 8];
                    int rn = wc + i * 16 + (lane & 15);
                    bfr[i] = *(const bf16x8*)&Bsm[rn * 64 + qs * 8];
                }
#pragma unroll
                for (int i = 0; i < 4; ++i)
#pragma unroll
                    for (int jn = 0; jn < 4; ++jn)
                        acc[i][jn] = __builtin_amdgcn_mfma_f32_16x16x32_bf16(
                            af[i], bfr[jn], acc[i][jn], 0, 0, 0);
            }
            __syncthreads();
        }
    }

    const int crow0 = bm + wr + (lane >> 4) * 4;
    const int ccol0 = bn + wc + (lane & 15);
#pragma unroll
    for (int i = 0; i < 4; ++i)
#pragma unroll
        for (int jn = 0; jn < 4; ++jn) {
            float bb = bias ? bias[ccol0 + jn * 16] : 0.f;
#pragma unroll
            for (int r = 0; r < 4; ++r)
                Y[(size_t)(crow0 + i * 16 + r) * CCH + ccol0 + jn * 16] =
                    acc[i][jn][r] + bb;
        }
}

// weight cast+transpose: Wc [pos][ci][co] f32 -> Wt [pos][co][ci] bf16
__global__ __launch_bounds__(256) void k_castw(
    const float* __restrict__ Wc, ushort_t* __restrict__ Wt)
{
    int pos = blockIdx.x >> 8, co = blockIdx.x & 255, ci = threadIdx.x;
    Wt[(size_t)(pos * 256 + co) * 256 + ci] =
        f2bf(Wc[(size_t)(pos * 256 + ci) * 256 + co]);
}

// bn+relu f32 -> bf16 cast (conv2 input)
__global__ __launch_bounds__(256) void k_castbn(
    const float* __restrict__ Yf, const float* __restrict__ par,
    ushort_t* __restrict__ Xb)
{
    size_t q = (size_t)blockIdx.x * 256 + threadIdx.x;  // float4 index
    int c = (int)(q & 63) * 4;
    float4 v = ((const float4*)Yf)[q];
    ushort4 o;
    o.x = f2bf(fmaxf(0.f, v.x * par[c + 0] + par[256 + c + 0]));
    o.y = f2bf(fmaxf(0.f, v.y * par[c + 1] + par[256 + c + 1]));
    o.z = f2bf(fmaxf(0.f, v.z * par[c + 2] + par[256 + c + 2]));
    o.w = f2bf(fmaxf(0.f, v.w * par[c + 3] + par[256 + c + 3]));
    ((ushort4*)Xb)[q] = o;
}

// ---------------------------------------------------------------- BN stats ---
__global__ void k_colstats(const float* __restrict__ Y, float* __restrict__ acc)
{
    const int ncols = blockDim.x;
    const int col = threadIdx.x;
    const int r0 = blockIdx.x * 256;
    float s = 0.f, q = 0.f;
    const float* p = Y + (size_t)r0 * ncols + col;
    for (int r = 0; r < 256; ++r, p += ncols) {
        float v = *p;
        s += v; q += v * v;
    }
    atomicAdd(&acc[col], s);
    atomicAdd(&acc[ncols + col], q);
}

__global__ void k_bnparams(const float* __restrict__ acc,
                           const float* __restrict__ g,
                           const float* __restrict__ b,
                           float* __restrict__ par, int ncols)
{
    int c = threadIdx.x;
    if (c >= ncols) return;
    float m = acc[c] * INV_S;
    float v = acc[ncols + c] * INV_S - m * m;
    float sc = g[c] * rsqrtf(v + EPS);
    par[c] = sc;
    par[ncols + c] = b[c] - m * sc;
}

// ---------------------------------------------------------------- head -------
// sp (bf16) written straight into Xb; Xb may alias B3 (same 8B/lane, RAW-safe)
__global__ __launch_bounds__(256) void k_headfin(
    const float* __restrict__ B2, const float* __restrict__ B3,
    const float* __restrict__ par1, const float* __restrict__ par3,
    const float* __restrict__ shw3, const float* __restrict__ shb3,
    const float* __restrict__ gw3, const float* __restrict__ gb3,
    const float* __restrict__ pooled, ushort_t* __restrict__ Xb)
{
    const int wave = threadIdx.x >> 6;
    const int lane = threadIdx.x & 63;
    const int s = blockIdx.x * 4 + wave;
    const float* b2 = B2 + (size_t)s * 256;
    const float* b3 = B3 + (size_t)s * 128;
    float d1 = 0.f, d2 = 0.f;
#pragma unroll
    for (int i = 0; i < 4; ++i) {
        int c = lane * 4 + i;
        float v = fmaxf(0.f, b2[c] * par1[c] + par1[256 + c]);
        d1 += v * shw3[c * 9];          // column 0 of [256,9]
    }
#pragma unroll
    for (int i = 0; i < 2; ++i) {
        int c = lane * 2 + i;
        float v = fmaxf(0.f, b3[c] * par3[c] + par3[128 + c]);
        d2 += v * gw3[c];
    }
#pragma unroll
    for (int off = 32; off > 0; off >>= 1) {
        d1 += __shfl_down(d1, off, 64);
        d2 += __shfl_down(d2, off, 64);
    }
    d1 = __shfl(d1, 0, 64);
    d2 = __shfl(d2, 0, 64);
    float shdc = d1 + shb3[0];
    float gaus = 1.f / (1.f + expf(-(d2 + gb3[0])));
    float factor = shdc * gaus;
    const float4* pr = (const float4*)(pooled + (size_t)s * 256);
    float4 v = pr[lane];
    ushort4 o;
    o.x = f2bf(v.x * factor);
    o.y = f2bf(v.y * factor);
    o.z = f2bf(v.z * factor);
    o.w = f2bf(v.w * factor);
    ((ushort4*)(Xb + (size_t)s * 256))[lane] = o;
}

// ---------------------------------------------------------------- final ------
__global__ __launch_bounds__(256) void k_bnrelu_inplace(
    float* __restrict__ Y, const float* __restrict__ par)
{
    size_t q = (size_t)blockIdx.x * 256 + threadIdx.x;  // float4 index
    int c = (int)(q & 63) * 4;
    float4* p = (float4*)Y;
    float4 v = p[q];
    v.x = fmaxf(0.f, v.x * par[c + 0] + par[256 + c + 0]);
    v.y = fmaxf(0.f, v.y * par[c + 1] + par[256 + c + 1]);
    v.z = fmaxf(0.f, v.z * par[c + 2] + par[256 + c + 2]);
    v.w = fmaxf(0.f, v.w * par[c + 3] + par[256 + c + 3]);
    p[q] = v;
}

// ---------------------------------------------------------------- launch -----
extern "C" void kernel_launch(void* const* d_in, const int* in_sizes, int n_in,
                              void* d_out, int out_size, void* d_ws, size_t ws_size,
                              hipStream_t stream)
{
    (void)in_sizes; (void)n_in; (void)out_size; (void)ws_size;
    const float* feats   = (const float*)d_in[0];
    const int*   cb      = (const int*)d_in[1];
    const int*   cy      = (const int*)d_in[2];
    const int*   cx      = (const int*)d_in[3];
    const float* sh_w1   = (const float*)d_in[4];
    const float* sh_g1   = (const float*)d_in[5];
    const float* sh_b1   = (const float*)d_in[6];
    const float* sh_w2   = (const float*)d_in[7];
    const float* sh_g2   = (const float*)d_in[8];
    const float* sh_b2   = (const float*)d_in[9];
    const float* sh_w3   = (const float*)d_in[10];
    const float* sh_bias3= (const float*)d_in[11];
    const float* g_w1    = (const float*)d_in[12];
    const float* g_g1    = (const float*)d_in[13];
    const float* g_b1    = (const float*)d_in[14];
    const float* g_w2    = (const float*)d_in[15];
    const float* g_g2    = (const float*)d_in[16];
    const float* g_b2    = (const float*)d_in[17];
    const float* g_w3    = (const float*)d_in[18];
    const float* g_bias3 = (const float*)d_in[19];
    const float* cw1     = (const float*)d_in[20];
    const float* c1_g    = (const float*)d_in[21];
    const float* c1_b    = (const float*)d_in[22];
    const float* cw2     = (const float*)d_in[23];
    const float* c2_bias = (const float*)d_in[24];
    const float* c2_g    = (const float*)d_in[25];
    const float* c2_b    = (const float*)d_in[26];

    float* out = (float*)d_out;               // also scratch B1
    float* ws  = (float*)d_ws;
    const size_t SB = (size_t)S_TOT * CCH;    // 36,044,800 floats
    float* P0  = ws;                          // pooled (sums); dead after headfin
    float* B2  = ws + SB;
    float* B3  = ws + 2 * SB;                 // S*128 f32; aliased by Xbf later
    float* CNT = ws + 2 * SB + (size_t)S_TOT * 128;
    float* ACC = CNT + S_TOT;                 // 6 * 512 floats
    float* PAR = ACC + 6 * 512;               // 6 * 512 floats
    float* B1  = out;
    // bf16 buffers carved from dead regions:
    ushort_t* Xbf = (ushort_t*)B3;            // [S][256] bf16 == S*128 f32 bytes
    ushort_t* WT1 = (ushort_t*)P0;            // 9*256*256 bf16 (after headfin)
    ushort_t* WT2 = WT1 + 9 * 256 * 256;
    ushort_t* ZP  = WT2 + 9 * 256 * 256;      // 4KB zero page

    hipMemsetAsync(P0, 0, SB * sizeof(float), stream);
    hipMemsetAsync(CNT, 0, (size_t)(S_TOT + 6 * 512) * sizeof(float), stream);

    // 1) scatter-mean pooling
    k_scatter_cnt<<<NPTS / 256, 256, 0, stream>>>(cb, cy, cx, CNT);
    k_scatter_feat<<<dim3(NPTS / 256, 64), 256, 0, stream>>>(feats, cb, cy, cx, P0);
    k_pool<<<35200, 256, 0, stream>>>(P0, CNT);

    // 2) SH head layer 1
    k_gemm<<<dim3(1100, 2), 256, 0, stream>>>(P0, sh_w1, B1, 256, 256, nullptr, nullptr);
    k_colstats<<<550, 256, 0, stream>>>(B1, ACC + 0 * 512);
    k_bnparams<<<1, 256, 0, stream>>>(ACC + 0 * 512, sh_g1, sh_b1, PAR + 0 * 512, 256);
    // 3) SH head layer 2
    k_gemm<<<dim3(1100, 2), 256, 0, stream>>>(B1, sh_w2, B2, 256, 256,
                                              PAR + 0 * 512, PAR + 0 * 512 + 256);
    k_colstats<<<550, 256, 0, stream>>>(B2, ACC + 1 * 512);
    k_bnparams<<<1, 256, 0, stream>>>(ACC + 1 * 512, sh_g2, sh_b2, PAR + 1 * 512, 256);
    // 4) G head layer 1
    k_gemm<<<dim3(1100, 2), 256, 0, stream>>>(P0, g_w1, B1, 256, 256, nullptr, nullptr);
    k_colstats<<<550, 256, 0, stream>>>(B1, ACC + 2 * 512);
    k_bnparams<<<1, 256, 0, stream>>>(ACC + 2 * 512, g_g1, g_b1, PAR + 2 * 512, 256);
    // 5) G head layer 2 (N = 128)
    k_gemm<<<dim3(1100, 1), 256, 0, stream>>>(B1, g_w2, B3, 128, 256,
                                              PAR + 2 * 512, PAR + 2 * 512 + 256);
    k_colstats<<<550, 128, 0, stream>>>(B3, ACC + 3 * 512);
    k_bnparams<<<1, 128, 0, stream>>>(ACC + 3 * 512, g_g2, g_b2, PAR + 3 * 512, 128);
    // 6) head finalize: sp (bf16) -> Xbf (aliases B3, row-for-row safe)
    k_headfin<<<35200, 256, 0, stream>>>(B2, B3, PAR + 1 * 512, PAR + 3 * 512,
                                         sh_w3, sh_bias3, g_w3, g_bias3, P0, Xbf);
    // 6b) weights -> bf16 [pos][co][ci] into dead P0 region; zero page
    k_castw<<<9 * 256, 256, 0, stream>>>(cw1, WT1);
    k_castw<<<9 * 256, 256, 0, stream>>>(cw2, WT2);
    hipMemsetAsync(ZP, 0, 4096, stream);
    // 7) conv1 (MFMA): B2 = conv3x3(Xbf)
    k_convmma<<<dim3(1100, 2), 256, 0, stream>>>(Xbf, WT1, B2, nullptr, ZP);
    k_colstats<<<550, 256, 0, stream>>>(B2, ACC + 4 * 512);
    k_bnparams<<<1, 256, 0, stream>>>(ACC + 4 * 512, c1_g, c1_b, PAR + 4 * 512, 256);
    // 7b) bnrelu(B2) -> bf16 Xbf
    k_castbn<<<35200, 256, 0, stream>>>(B2, PAR + 4 * 512, Xbf);
    // 8) conv2 (MFMA): out = conv3x3(Xbf) + bias
    k_convmma<<<dim3(1100, 2), 256, 0, stream>>>(Xbf, WT2, out, c2_bias, ZP);
    k_colstats<<<550, 256, 0, stream>>>(out, ACC + 5 * 512);
    k_bnparams<<<1, 256, 0, stream>>>(ACC + 5 * 512, c2_g, c2_b, PAR + 5 * 512, 256);
    // 9) final BN+ReLU in place
    k_bnrelu_inplace<<<35200, 256, 0, stream>>>(out, PAR + 5 * 512);
}

// Round 3
// 1022.121 us; speedup vs baseline: 6.1004x; 2.4363x over previous
//
#include <hip/hip_runtime.h>
#include <hip/hip_bf16.h>
#include <cstdint>
#include <cstddef>

// Problem constants
#define B_DIM 4
#define H_DIM 200
#define W_DIM 176
#define CCH 256
#define NPP 16384        // points per batch entry (N)
#define NPTS 65536       // total points (P)
#define HW 35200         // H*W
#define S_TOT 140800     // B*H*W
#define EPS 1e-3f
#define INV_S (1.0f/140800.0f)

typedef unsigned short ushort_t;
typedef __attribute__((ext_vector_type(8))) short bf16x8;
typedef __attribute__((ext_vector_type(4))) float f32x4;

__device__ __forceinline__ ushort_t f2bf(float f) {
    __hip_bfloat16 h = __float2bfloat16(f);   // RNE
    return *(ushort_t*)&h;
}
__device__ __forceinline__ float bf2f(ushort_t u) {
    __hip_bfloat16 h = *(__hip_bfloat16*)&u;
    return __bfloat162float(h);
}

__device__ __forceinline__ void async16(const void* g, void* l) {
    __builtin_amdgcn_global_load_lds(
        (const __attribute__((address_space(1))) unsigned int*)g,
        (__attribute__((address_space(3))) unsigned int*)l,
        16, 0, 0);
}

// ---------------------------------------------------------------- transpose --
// feats [4][256][16384] f32  ->  FT [65536][256] f32   (point-major)
__global__ __launch_bounds__(256) void k_transpose(
    const float* __restrict__ feats, float* __restrict__ FT)
{
    __shared__ float lds[64][65];
    const int b  = blockIdx.z;
    const int c0 = blockIdx.y * 64;
    const int n0 = blockIdx.x * 64;
    const int tid = threadIdx.x;
#pragma unroll
    for (int i = 0; i < 16; ++i) {
        int idx = i * 256 + tid;
        int cr = idx >> 6, nc = idx & 63;
        lds[cr][nc] = feats[((size_t)b * 256 + c0 + cr) * NPP + n0 + nc];
    }
    __syncthreads();
#pragma unroll
    for (int i = 0; i < 16; ++i) {
        int idx = i * 256 + tid;
        int nr = idx >> 6, cc = idx & 63;
        FT[((size_t)b * NPP + n0 + nr) * CCH + c0 + cc] = lds[cc][nr];
    }
}

// ---------------------------------------------------------------- index build
__global__ __launch_bounds__(256) void k_buildidx(
    const int* __restrict__ cb, const int* __restrict__ cy,
    const int* __restrict__ cx, int* __restrict__ cnt,
    int* __restrict__ pslot, int* __restrict__ vid)
{
    int p = blockIdx.x * 256 + threadIdx.x;
    int v = cb[p] * HW + cy[p] * W_DIM + cx[p];
    vid[p] = v;
    int r = atomicAdd(&cnt[v], 1);
    if (r < 8) pslot[v * 8 + r] = p;
}

// ---------------------------------------------------------------- pool gather
// one wave per voxel; writes EVERY row (zeros for empty) as bf16
__global__ __launch_bounds__(256) void k_poolgather(
    const float* __restrict__ FT, const int* __restrict__ cnt,
    const int* __restrict__ pslot, const int* __restrict__ vid,
    ushort_t* __restrict__ Pb)
{
    const int wave = threadIdx.x >> 6;
    const int lane = threadIdx.x & 63;
    const int v = blockIdx.x * 4 + wave;
    const int c = cnt[v];
    float4 a = make_float4(0.f, 0.f, 0.f, 0.f);
    if (c <= 8) {
        for (int k = 0; k < c; ++k) {
            int p = pslot[v * 8 + k];
            float4 r = ((const float4*)(FT + (size_t)p * CCH))[lane];
            a.x += r.x; a.y += r.y; a.z += r.z; a.w += r.w;
        }
    } else {  // overflow fallback (statistically never taken)
        for (int p = 0; p < NPTS; ++p)
            if (vid[p] == v) {
                float4 r = ((const float4*)(FT + (size_t)p * CCH))[lane];
                a.x += r.x; a.y += r.y; a.z += r.z; a.w += r.w;
            }
    }
    float inv = c ? 1.f / (float)c : 0.f;
    ushort4 o;
    o.x = f2bf(a.x * inv); o.y = f2bf(a.y * inv);
    o.z = f2bf(a.z * inv); o.w = f2bf(a.w * inv);
    ((ushort4*)(Pb + (size_t)v * CCH))[lane] = o;
}

// ---------------------------------------------------------------- MFMA GEMM --
// Yb[M,N] bf16 = X[M,256] bf16 @ Wt[N,256]^T bf16. Tile 128x128, BK=64.
// LDS XOR-swizzled in 16B units: phys_q = log_q ^ (row&7).
__global__ __launch_bounds__(256) void k_gemmma(
    const ushort_t* __restrict__ X, const ushort_t* __restrict__ Wt,
    ushort_t* __restrict__ Yb, int N)
{
    __shared__ ushort_t Asm[128 * 64];
    __shared__ ushort_t Bsm[128 * 64];
    const int tid  = threadIdx.x;
    const int w    = tid >> 6;
    const int lane = tid & 63;
    const int bm   = blockIdx.x * 128;
    const int bn   = blockIdx.y * 128;
    const int wr   = (w >> 1) * 64;
    const int wc   = (w & 1) * 64;

    size_t aoff[4]; size_t boff[4];
#pragma unroll
    for (int j = 0; j < 4; ++j) {
        int row  = 32 * w + 8 * j + (lane >> 3);
        int qlog = (lane & 7) ^ (row & 7);
        aoff[j] = (size_t)(bm + row) * 256 + qlog * 8;
        boff[j] = (size_t)(bn + row) * 256 + qlog * 8;
    }

    f32x4 acc[4][4] = {};
    for (int kc = 0; kc < 256; kc += 64) {
#pragma unroll
        for (int j = 0; j < 4; ++j)
            async16(X + aoff[j] + kc, Asm + w * 2048 + j * 512);
#pragma unroll
        for (int j = 0; j < 4; ++j)
            async16(Wt + boff[j] + kc, Bsm + w * 2048 + j * 512);
        __syncthreads();
#pragma unroll
        for (int ks = 0; ks < 2; ++ks) {
            bf16x8 af[4], bfr[4];
            const int qs = (ks * 4 + (lane >> 4)) ^ (lane & 7);
#pragma unroll
            for (int i = 0; i < 4; ++i) {
                int r  = wr + i * 16 + (lane & 15);
                af[i]  = *(const bf16x8*)&Asm[r * 64 + qs * 8];
                int rn = wc + i * 16 + (lane & 15);
                bfr[i] = *(const bf16x8*)&Bsm[rn * 64 + qs * 8];
            }
#pragma unroll
            for (int i = 0; i < 4; ++i)
#pragma unroll
                for (int jn = 0; jn < 4; ++jn)
                    acc[i][jn] = __builtin_amdgcn_mfma_f32_16x16x32_bf16(
                        af[i], bfr[jn], acc[i][jn], 0, 0, 0);
        }
        __syncthreads();
    }
    const int crow0 = bm + wr + (lane >> 4) * 4;
    const int ccol0 = bn + wc + (lane & 15);
#pragma unroll
    for (int i = 0; i < 4; ++i)
#pragma unroll
        for (int jn = 0; jn < 4; ++jn)
#pragma unroll
            for (int r = 0; r < 4; ++r)
                Yb[(size_t)(crow0 + i * 16 + r) * N + ccol0 + jn * 16] =
                    f2bf(acc[i][jn][r]);
}

// ---------------------------------------------------------------- conv MFMA --
// conv3x3(X as [B,H,W,256] bf16) @ Wt[9][co][ci] bf16 (+bias)
// output: bf16 (Yb) or f32 (Yf) — exactly one non-null.
__global__ __launch_bounds__(256) void k_convmma(
    const ushort_t* __restrict__ X, const ushort_t* __restrict__ Wt,
    float* __restrict__ Yf, ushort_t* __restrict__ Yb,
    const float* __restrict__ bias, const ushort_t* __restrict__ zp)
{
    __shared__ ushort_t Asm[128 * 64];
    __shared__ ushort_t Bsm[128 * 64];
    const int tid  = threadIdx.x;
    const int w    = tid >> 6;
    const int lane = tid & 63;
    const int bm   = blockIdx.x * 128;
    const int bn   = blockIdx.y * 128;
    const int wr   = (w >> 1) * 64;
    const int wc   = (w & 1) * 64;

    int yj[4], xj[4];
    const ushort_t* abase[4];
    int boff[4];
#pragma unroll
    for (int j = 0; j < 4; ++j) {
        int row  = 32 * w + 8 * j + (lane >> 3);
        int qlog = (lane & 7) ^ (row & 7);
        int s    = bm + row;
        yj[j] = (s / W_DIM) % H_DIM;
        xj[j] = s % W_DIM;
        abase[j] = X + (size_t)s * CCH + qlog * 8;
        boff[j]  = (bn + row) * CCH + qlog * 8;
    }

    f32x4 acc[4][4] = {};
    for (int pos = 0; pos < 9; ++pos) {
        const int dy = pos / 3 - 1, dx = pos % 3 - 1;
        const ushort_t* bw = Wt + pos * (CCH * CCH);
        const ushort_t* ap[4];
#pragma unroll
        for (int j = 0; j < 4; ++j) {
            bool ok = ((unsigned)(yj[j] + dy) < (unsigned)H_DIM) &&
                      ((unsigned)(xj[j] + dx) < (unsigned)W_DIM);
            ap[j] = ok ? abase[j] + (dy * W_DIM + dx) * CCH : zp + lane * 8;
        }
        for (int kc = 0; kc < CCH; kc += 64) {
#pragma unroll
            for (int j = 0; j < 4; ++j)
                async16(ap[j] + kc, Asm + w * 2048 + j * 512);
#pragma unroll
            for (int j = 0; j < 4; ++j)
                async16(bw + boff[j] + kc, Bsm + w * 2048 + j * 512);
            __syncthreads();
#pragma unroll
            for (int ks = 0; ks < 2; ++ks) {
                bf16x8 af[4], bfr[4];
                const int qs = (ks * 4 + (lane >> 4)) ^ (lane & 7);
#pragma unroll
                for (int i = 0; i < 4; ++i) {
                    int r  = wr + i * 16 + (lane & 15);
                    af[i]  = *(const bf16x8*)&Asm[r * 64 + qs * 8];
                    int rn = wc + i * 16 + (lane & 15);
                    bfr[i] = *(const bf16x8*)&Bsm[rn * 64 + qs * 8];
                }
#pragma unroll
                for (int i = 0; i < 4; ++i)
#pragma unroll
                    for (int jn = 0; jn < 4; ++jn)
                        acc[i][jn] = __builtin_amdgcn_mfma_f32_16x16x32_bf16(
                            af[i], bfr[jn], acc[i][jn], 0, 0, 0);
            }
            __syncthreads();
        }
    }

    const int crow0 = bm + wr + (lane >> 4) * 4;
    const int ccol0 = bn + wc + (lane & 15);
#pragma unroll
    for (int i = 0; i < 4; ++i)
#pragma unroll
        for (int jn = 0; jn < 4; ++jn) {
            float bb = bias ? bias[ccol0 + jn * 16] : 0.f;
#pragma unroll
            for (int r = 0; r < 4; ++r) {
                float v = acc[i][jn][r] + bb;
                size_t o = (size_t)(crow0 + i * 16 + r) * CCH + ccol0 + jn * 16;
                if (Yb) Yb[o] = f2bf(v); else Yf[o] = v;
            }
        }
}

// weight cast+transpose: Wc [pos][ci][CO] f32 -> Wt [pos*CO+co][256 ci] bf16
__global__ __launch_bounds__(256) void k_castw(
    const float* __restrict__ Wc, ushort_t* __restrict__ Wt, int CO)
{
    int pc = blockIdx.x;              // pos*CO + co
    int co = pc % CO, pos = pc / CO, ci = threadIdx.x;
    Wt[(size_t)pc * 256 + ci] = f2bf(Wc[((size_t)pos * 256 + ci) * CO + co]);
}

// ---------------------------------------------------------------- BN stats ---
__global__ void k_colstats_bf(const ushort_t* __restrict__ Y,
                              float* __restrict__ acc)
{
    const int ncols = blockDim.x;
    const int col = threadIdx.x;
    const int r0 = blockIdx.x * 256;
    float s = 0.f, q = 0.f;
    const ushort_t* p = Y + (size_t)r0 * ncols + col;
    for (int r = 0; r < 256; ++r, p += ncols) {
        float v = bf2f(*p);
        s += v; q += v * v;
    }
    atomicAdd(&acc[col], s);
    atomicAdd(&acc[ncols + col], q);
}

__global__ void k_colstats(const float* __restrict__ Y, float* __restrict__ acc)
{
    const int ncols = blockDim.x;
    const int col = threadIdx.x;
    const int r0 = blockIdx.x * 256;
    float s = 0.f, q = 0.f;
    const float* p = Y + (size_t)r0 * ncols + col;
    for (int r = 0; r < 256; ++r, p += ncols) {
        float v = *p;
        s += v; q += v * v;
    }
    atomicAdd(&acc[col], s);
    atomicAdd(&acc[ncols + col], q);
}

__global__ void k_bnparams(const float* __restrict__ acc,
                           const float* __restrict__ g,
                           const float* __restrict__ b,
                           float* __restrict__ par, int ncols)
{
    int c = threadIdx.x;
    if (c >= ncols) return;
    float m = acc[c] * INV_S;
    float v = acc[ncols + c] * INV_S - m * m;
    float sc = g[c] * rsqrtf(v + EPS);
    par[c] = sc;
    par[ncols + c] = b[c] - m * sc;
}

// in-place BN+ReLU on a [S][256] bf16 buffer
__global__ __launch_bounds__(256) void k_bnrelu_bf(
    ushort_t* __restrict__ Y, const float* __restrict__ par)
{
    size_t q = (size_t)blockIdx.x * 256 + threadIdx.x;  // ushort4 index
    int c = (int)(q & 63) * 4;
    ushort4 u = ((ushort4*)Y)[q];
    u.x = f2bf(fmaxf(0.f, bf2f(u.x) * par[c + 0] + par[256 + c + 0]));
    u.y = f2bf(fmaxf(0.f, bf2f(u.y) * par[c + 1] + par[256 + c + 1]));
    u.z = f2bf(fmaxf(0.f, bf2f(u.z) * par[c + 2] + par[256 + c + 2]));
    u.w = f2bf(fmaxf(0.f, bf2f(u.w) * par[c + 3] + par[256 + c + 3]));
    ((ushort4*)Y)[q] = u;
}

// ---------------------------------------------------------------- head -------
__global__ __launch_bounds__(256) void k_headfin(
    const ushort_t* __restrict__ B2, const ushort_t* __restrict__ B3,
    const float* __restrict__ par1, const float* __restrict__ par3,
    const float* __restrict__ shw3, const float* __restrict__ shb3,
    const float* __restrict__ gw3, const float* __restrict__ gb3,
    const ushort_t* __restrict__ Pb, ushort_t* __restrict__ Xb)
{
    const int wave = threadIdx.x >> 6;
    const int lane = threadIdx.x & 63;
    const int s = blockIdx.x * 4 + wave;
    const ushort_t* b2 = B2 + (size_t)s * 256;
    const ushort_t* b3 = B3 + (size_t)s * 128;
    float d1 = 0.f, d2 = 0.f;
    {
        ushort4 u = ((const ushort4*)b2)[lane];
        int c = lane * 4;
        float v0 = fmaxf(0.f, bf2f(u.x) * par1[c + 0] + par1[256 + c + 0]);
        float v1 = fmaxf(0.f, bf2f(u.y) * par1[c + 1] + par1[256 + c + 1]);
        float v2 = fmaxf(0.f, bf2f(u.z) * par1[c + 2] + par1[256 + c + 2]);
        float v3 = fmaxf(0.f, bf2f(u.w) * par1[c + 3] + par1[256 + c + 3]);
        d1 = v0 * shw3[(c + 0) * 9] + v1 * shw3[(c + 1) * 9]
           + v2 * shw3[(c + 2) * 9] + v3 * shw3[(c + 3) * 9];
    }
    {
        ushort2 u = ((const ushort2*)b3)[lane];
        int c = lane * 2;
        float v0 = fmaxf(0.f, bf2f(u.x) * par3[c + 0] + par3[128 + c + 0]);
        float v1 = fmaxf(0.f, bf2f(u.y) * par3[c + 1] + par3[128 + c + 1]);
        d2 = v0 * gw3[c + 0] + v1 * gw3[c + 1];
    }
#pragma unroll
    for (int off = 32; off > 0; off >>= 1) {
        d1 += __shfl_down(d1, off, 64);
        d2 += __shfl_down(d2, off, 64);
    }
    d1 = __shfl(d1, 0, 64);
    d2 = __shfl(d2, 0, 64);
    float shdc = d1 + shb3[0];
    float gaus = 1.f / (1.f + expf(-(d2 + gb3[0])));
    float factor = shdc * gaus;
    ushort4 pv = ((const ushort4*)(Pb + (size_t)s * 256))[lane];
    ushort4 o;
    o.x = f2bf(bf2f(pv.x) * factor);
    o.y = f2bf(bf2f(pv.y) * factor);
    o.z = f2bf(bf2f(pv.z) * factor);
    o.w = f2bf(bf2f(pv.w) * factor);
    ((ushort4*)(Xb + (size_t)s * 256))[lane] = o;
}

// ---------------------------------------------------------------- final ------
__global__ __launch_bounds__(256) void k_bnrelu_inplace(
    float* __restrict__ Y, const float* __restrict__ par)
{
    size_t q = (size_t)blockIdx.x * 256 + threadIdx.x;  // float4 index
    int c = (int)(q & 63) * 4;
    float4* p = (float4*)Y;
    float4 v = p[q];
    v.x = fmaxf(0.f, v.x * par[c + 0] + par[256 + c + 0]);
    v.y = fmaxf(0.f, v.y * par[c + 1] + par[256 + c + 1]);
    v.z = fmaxf(0.f, v.z * par[c + 2] + par[256 + c + 2]);
    v.w = fmaxf(0.f, v.w * par[c + 3] + par[256 + c + 3]);
    p[q] = v;
}

// ---------------------------------------------------------------- launch -----
extern "C" void kernel_launch(void* const* d_in, const int* in_sizes, int n_in,
                              void* d_out, int out_size, void* d_ws, size_t ws_size,
                              hipStream_t stream)
{
    (void)in_sizes; (void)n_in; (void)out_size; (void)ws_size;
    const float* feats   = (const float*)d_in[0];
    const int*   cb      = (const int*)d_in[1];
    const int*   cy      = (const int*)d_in[2];
    const int*   cx      = (const int*)d_in[3];
    const float* sh_w1   = (const float*)d_in[4];
    const float* sh_g1   = (const float*)d_in[5];
    const float* sh_b1   = (const float*)d_in[6];
    const float* sh_w2   = (const float*)d_in[7];
    const float* sh_g2   = (const float*)d_in[8];
    const float* sh_b2   = (const float*)d_in[9];
    const float* sh_w3   = (const float*)d_in[10];
    const float* sh_bias3= (const float*)d_in[11];
    const float* g_w1    = (const float*)d_in[12];
    const float* g_g1    = (const float*)d_in[13];
    const float* g_b1    = (const float*)d_in[14];
    const float* g_w2    = (const float*)d_in[15];
    const float* g_g2    = (const float*)d_in[16];
    const float* g_b2    = (const float*)d_in[17];
    const float* g_w3    = (const float*)d_in[18];
    const float* g_bias3 = (const float*)d_in[19];
    const float* cw1     = (const float*)d_in[20];
    const float* c1_g    = (const float*)d_in[21];
    const float* c1_b    = (const float*)d_in[22];
    const float* cw2     = (const float*)d_in[23];
    const float* c2_bias = (const float*)d_in[24];
    const float* c2_g    = (const float*)d_in[25];
    const float* c2_b    = (const float*)d_in[26];

    float* out = (float*)d_out;
    float* ws  = (float*)d_ws;
    // float-slot offsets (proven ws budget ~344 MB; this plan uses ~313 MB)
    ushort_t* Pb   = (ushort_t*)(ws);                    // pooled bf16 [S][256]
    ushort_t* Bb   = (ushort_t*)(ws + 18022400);         // scratch bf16 [S][256]
    ushort_t* Cb   = (ushort_t*)(ws + 36044800);         // B2 bf16 [S][256]
    float*    FT   = (float*)(ws + 36044800);            // aliases Cb (pool phase)
    ushort_t* Db   = (ushort_t*)(ws + 54067200);         // B3 bf16 [S][128]
    int*      CNTi = (int*)(ws + 54067200);              // aliases Db (pool phase)
    int*      PSL  = CNTi + S_TOT;                       // [S*8]
    int*      VID  = PSL + S_TOT * 8;                    // [P]
    ushort_t* Eb   = (ushort_t*)(ws + 63078400);         // conv1 out bf16 [S][256]
    ushort_t* WT1  = (ushort_t*)(ws + 81100800);         // 9*256*256
    ushort_t* WT2  = WT1 + 589824;
    ushort_t* WS1  = WT2 + 589824;
    ushort_t* WS2  = WS1 + 65536;
    ushort_t* WG1  = WS2 + 65536;
    ushort_t* WG2  = WG1 + 65536;                        // 128*256
    ushort_t* ZP   = WG2 + 32768;                        // 4KB zero page
    float*    ACC  = (float*)(ZP + 2048);                // 6 * 512
    float*    PAR  = ACC + 6 * 512;                      // 6 * 512

    hipMemsetAsync(CNTi, 0, (size_t)S_TOT * 4, stream);
    hipMemsetAsync(ACC, 0, 6 * 512 * 4, stream);
    hipMemsetAsync(ZP, 0, 4096, stream);

    // weights -> bf16 [co][ci]
    k_castw<<<9 * 256, 256, 0, stream>>>(cw1, WT1, 256);
    k_castw<<<9 * 256, 256, 0, stream>>>(cw2, WT2, 256);
    k_castw<<<256, 256, 0, stream>>>(sh_w1, WS1, 256);
    k_castw<<<256, 256, 0, stream>>>(sh_w2, WS2, 256);
    k_castw<<<256, 256, 0, stream>>>(g_w1, WG1, 256);
    k_castw<<<128, 256, 0, stream>>>(g_w2, WG2, 128);

    // 1) pooling: transpose -> index build -> gather-mean (no float atomics)
    k_transpose<<<dim3(256, 4, 4), 256, 0, stream>>>(feats, FT);
    k_buildidx<<<NPTS / 256, 256, 0, stream>>>(cb, cy, cx, CNTi, PSL, VID);
    k_poolgather<<<S_TOT / 4, 256, 0, stream>>>(FT, CNTi, PSL, VID, Pb);

    // 2) SH layer 1: Bb = Pb @ WS1 ; stats ; bnrelu in place
    k_gemmma<<<dim3(1100, 2), 256, 0, stream>>>(Pb, WS1, Bb, 256);
    k_colstats_bf<<<550, 256, 0, stream>>>(Bb, ACC + 0 * 512);
    k_bnparams<<<1, 256, 0, stream>>>(ACC + 0 * 512, sh_g1, sh_b1, PAR + 0 * 512, 256);
    k_bnrelu_bf<<<35200, 256, 0, stream>>>(Bb, PAR + 0 * 512);
    // 3) SH layer 2: Cb = Bb @ WS2 ; stats
    k_gemmma<<<dim3(1100, 2), 256, 0, stream>>>(Bb, WS2, Cb, 256);
    k_colstats_bf<<<550, 256, 0, stream>>>(Cb, ACC + 1 * 512);
    k_bnparams<<<1, 256, 0, stream>>>(ACC + 1 * 512, sh_g2, sh_b2, PAR + 1 * 512, 256);
    // 4) G layer 1: Bb = Pb @ WG1 ; stats ; bnrelu in place
    k_gemmma<<<dim3(1100, 2), 256, 0, stream>>>(Pb, WG1, Bb, 256);
    k_colstats_bf<<<550, 256, 0, stream>>>(Bb, ACC + 2 * 512);
    k_bnparams<<<1, 256, 0, stream>>>(ACC + 2 * 512, g_g1, g_b1, PAR + 2 * 512, 256);
    k_bnrelu_bf<<<35200, 256, 0, stream>>>(Bb, PAR + 2 * 512);
    // 5) G layer 2: Db = Bb @ WG2 (N=128) ; stats
    k_gemmma<<<dim3(1100, 1), 256, 0, stream>>>(Bb, WG2, Db, 128);
    k_colstats_bf<<<550, 128, 0, stream>>>(Db, ACC + 3 * 512);
    k_bnparams<<<1, 128, 0, stream>>>(ACC + 3 * 512, g_g2, g_b2, PAR + 3 * 512, 128);
    // 6) head finalize -> Bb (conv1 input, bf16)
    k_headfin<<<S_TOT / 4, 256, 0, stream>>>(Cb, Db, PAR + 1 * 512, PAR + 3 * 512,
                                             sh_w3, sh_bias3, g_w3, g_bias3, Pb, Bb);
    // 7) conv1 (MFMA): Eb = conv3x3(Bb) bf16 ; stats ; bnrelu in place
    k_convmma<<<dim3(1100, 2), 256, 0, stream>>>(Bb, WT1, nullptr, Eb, nullptr, ZP);
    k_colstats_bf<<<550, 256, 0, stream>>>(Eb, ACC + 4 * 512);
    k_bnparams<<<1, 256, 0, stream>>>(ACC + 4 * 512, c1_g, c1_b, PAR + 4 * 512, 256);
    k_bnrelu_bf<<<35200, 256, 0, stream>>>(Eb, PAR + 4 * 512);
    // 8) conv2 (MFMA): out = conv3x3(Eb) + bias (f32) ; stats ; final bnrelu
    k_convmma<<<dim3(1100, 2), 256, 0, stream>>>(Eb, WT2, out, nullptr, c2_bias, ZP);
    k_colstats<<<550, 256, 0, stream>>>(out, ACC + 5 * 512);
    k_bnparams<<<1, 256, 0, stream>>>(ACC + 5 * 512, c2_g, c2_b, PAR + 5 * 512, 256);
    k_bnrelu_inplace<<<35200, 256, 0, stream>>>(out, PAR + 5 * 512);
}